// Round 3
// baseline (633.908 us; speedup 1.0000x reference)
//
#include <hip/hip_runtime.h>
#include <math.h>

typedef __attribute__((ext_vector_type(8))) short short8;   // 8 x bf16 bits
typedef __attribute__((ext_vector_type(8))) __bf16 bf16x8;  // MFMA operand type
typedef __attribute__((ext_vector_type(4))) float f32x4;
typedef unsigned short ushort_t;

#define DEV __device__ __forceinline__

// ---------------- problem constants ----------------
constexpr int Dm   = 512;
constexpr int DI   = 1024;
constexpr int DR   = 32;
constexpr int Hh   = 16;
constexpr int Wd   = 11;
constexpr int Bm   = 10;          // b * (Sf/T) = 2*5
constexpr int Lq   = 528;         // T*H*W
constexpr int NTOK = Bm * Lq;     // 5280
constexpr int MBAT = 4 * Bm;      // 40 (4 scan paths)
constexpr int MTOK = MBAT * Lq;   // 21120
constexpr int XD_LD = 40;         // padded ld for x_dbl (34 cols used)

// ---------------- bf16 helpers (explicit RNE) ----------------
DEV ushort_t f2bf(float f) {
    unsigned u = __float_as_uint(f);
    u += 0x7fffu + ((u >> 16) & 1u);
    return (ushort_t)(u >> 16);
}
DEV float bf2f(ushort_t h) { return __uint_as_float(((unsigned)h) << 16); }

DEV bf16x8 as_bf(short8 v) { return __builtin_bit_cast(bf16x8, v); }

DEV void mfma_bf16(f32x4& d, short8 a, short8 b) {
    d = __builtin_amdgcn_mfma_f32_16x16x32_bf16(as_bf(a), as_bf(b), d, 0, 0, 0);
}

// ---------------- f32 -> bf16 weight convert ----------------
__global__ void k_f2bf(const float* __restrict__ s, ushort_t* __restrict__ d, int n) {
    int i = blockIdx.x * 256 + threadIdx.x;
    if (i < n) d[i] = f2bf(s[i]);
}

// ---------------- LN1 + 4-path scatter into cat ----------------
__global__ void k_ln1(const float* __restrict__ x, const float* __restrict__ g,
                      const float* __restrict__ b, ushort_t* __restrict__ cat) {
    const int tok  = blockIdx.x;     // 0..NTOK-1, order = (b, t, h, w)
    const int lane = threadIdx.x;    // 64 threads
    const int c0   = lane * 8;
    const float* row = x + (size_t)tok * Dm;
    float4 v0 = *(const float4*)(row + c0);
    float4 v1 = *(const float4*)(row + c0 + 4);
    float s  = v0.x + v0.y + v0.z + v0.w + v1.x + v1.y + v1.z + v1.w;
    float ss = v0.x*v0.x + v0.y*v0.y + v0.z*v0.z + v0.w*v0.w
             + v1.x*v1.x + v1.y*v1.y + v1.z*v1.z + v1.w*v1.w;
#pragma unroll
    for (int o = 32; o >= 1; o >>= 1) { s += __shfl_xor(s, o); ss += __shfl_xor(ss, o); }
    const float mean = s * (1.0f / Dm);
    const float rstd = rsqrtf(ss * (1.0f / Dm) - mean * mean + 1e-5f);
    float4 g0 = *(const float4*)(g + c0), g1 = *(const float4*)(g + c0 + 4);
    float4 b0 = *(const float4*)(b + c0), b1 = *(const float4*)(b + c0 + 4);
    union { uint4 u; ushort_t h[8]; } pk;
    pk.h[0] = f2bf((v0.x - mean) * rstd * g0.x + b0.x);
    pk.h[1] = f2bf((v0.y - mean) * rstd * g0.y + b0.y);
    pk.h[2] = f2bf((v0.z - mean) * rstd * g0.z + b0.z);
    pk.h[3] = f2bf((v0.w - mean) * rstd * g0.w + b0.w);
    pk.h[4] = f2bf((v1.x - mean) * rstd * g1.x + b1.x);
    pk.h[5] = f2bf((v1.y - mean) * rstd * g1.y + b1.y);
    pk.h[6] = f2bf((v1.z - mean) * rstd * g1.z + b1.z);
    pk.h[7] = f2bf((v1.w - mean) * rstd * g1.w + b1.w);
    const int bi = tok / Lq;
    const int l1 = tok % Lq;                 // (t*H + h)*W + w
    const int t  = l1 / (Hh * Wd);
    const int hw = l1 % (Hh * Wd);
    const int hh = hw / Wd, ww = hw % Wd;
    const int l3 = (t * Wd + ww) * Hh + hh;  // (t*W + w)*H + h
    *(uint4*)(cat + ((size_t)(0 * Bm + bi) * Lq + l1           ) * Dm + c0) = pk.u;
    *(uint4*)(cat + ((size_t)(1 * Bm + bi) * Lq + (Lq - 1 - l1)) * Dm + c0) = pk.u;
    *(uint4*)(cat + ((size_t)(2 * Bm + bi) * Lq + l3           ) * Dm + c0) = pk.u;
    *(uint4*)(cat + ((size_t)(3 * Bm + bi) * Lq + (Lq - 1 - l3)) * Dm + c0) = pk.u;
}

// ---------------- generic C = A @ B^T  (A: MxK bf16, B: NxK bf16) ----------------
// EPI 0: bf16 store | 1: softplus(acc+bias) f32 | 2: gelu(acc+bias) bf16 | 3: acc+bias+resid f32
template<int EPI>
__launch_bounds__(256)
__global__ void k_gemm_bt(const ushort_t* __restrict__ A, const ushort_t* __restrict__ B,
                          void* __restrict__ C, int M, int N, int K,
                          int lda, int ldb, int ldc,
                          const float* __restrict__ bias, const float* __restrict__ resid) {
    constexpr int BM = 64, BN = 64, BK = 64, LDL = BK + 8;  // +8 bf16 pad = 16B, kills worst bank conflicts
    __shared__ __align__(16) ushort_t As[BM][LDL];
    __shared__ __align__(16) ushort_t Bs[BN][LDL];
    const int tid  = threadIdx.x;
    const int m0   = blockIdx.x * BM, n0 = blockIdx.y * BN;
    const int lane = tid & 63;
    const int wv   = tid >> 6;
    const int wm   = wv >> 1, wn = wv & 1;
    const int lr   = lane & 15, lg = lane >> 4;

    f32x4 acc[2][2] = {};

    for (int kb = 0; kb < K; kb += BK) {
#pragma unroll
        for (int j = 0; j < 2; ++j) {
            const int chunk = tid + j * 256;          // 512 chunks of 8 bf16
            const int row = chunk >> 3;
            const int k0  = (chunk & 7) << 3;
            const int gk  = kb + k0;
            short8 va = {};
            const int gm = m0 + row;
            if (gm < M && gk < K) va = *(const short8*)(A + (size_t)gm * lda + gk);
            *(short8*)(&As[row][k0]) = va;
            short8 vb = {};
            const int gn = n0 + row;
            if (gn < N && gk < K) vb = *(const short8*)(B + (size_t)gn * ldb + gk);
            *(short8*)(&Bs[row][k0]) = vb;
        }
        __syncthreads();
#pragma unroll
        for (int kk = 0; kk < 2; ++kk) {
            short8 a0 = *(const short8*)(&As[wm * 32 +  0 + lr][kk * 32 + lg * 8]);
            short8 a1 = *(const short8*)(&As[wm * 32 + 16 + lr][kk * 32 + lg * 8]);
            short8 b0 = *(const short8*)(&Bs[wn * 32 +  0 + lr][kk * 32 + lg * 8]);
            short8 b1 = *(const short8*)(&Bs[wn * 32 + 16 + lr][kk * 32 + lg * 8]);
            mfma_bf16(acc[0][0], a0, b0);
            mfma_bf16(acc[0][1], a0, b1);
            mfma_bf16(acc[1][0], a1, b0);
            mfma_bf16(acc[1][1], a1, b1);
        }
        __syncthreads();
    }

#pragma unroll
    for (int mf = 0; mf < 2; ++mf)
#pragma unroll
        for (int nf = 0; nf < 2; ++nf) {
            const int gc = n0 + wn * 32 + nf * 16 + lr;
            if (gc >= N) continue;
#pragma unroll
            for (int r = 0; r < 4; ++r) {
                const int gm = m0 + wm * 32 + mf * 16 + lg * 4 + r;
                if (gm >= M) continue;
                float v = acc[mf][nf][r];
                const size_t oi = (size_t)gm * ldc + gc;
                if constexpr (EPI == 0) {
                    ((ushort_t*)C)[oi] = f2bf(v);
                } else if constexpr (EPI == 1) {
                    v += bias[gc];
                    v = (v > 20.0f) ? v : log1pf(__expf(v));
                    ((float*)C)[oi] = v;
                } else if constexpr (EPI == 2) {
                    v += bias[gc];
                    v = 0.5f * v * (1.0f + erff(v * 0.70710678118654752f));
                    ((ushort_t*)C)[oi] = f2bf(v);
                } else {
                    v += bias[gc] + resid[oi];
                    ((float*)C)[oi] = v;   // d_out is float32 (reference output dtype)
                }
            }
        }
}

// ---------------- depthwise causal conv (DC=4) + SiLU ----------------
__global__ void k_conv(const ushort_t* __restrict__ xz, const float* __restrict__ cw,
                       const float* __restrict__ cb, ushort_t* __restrict__ xi) {
    const int idx = blockIdx.x * 256 + threadIdx.x;
    if (idx >= MTOK * DI) return;
    const int ch = idx & (DI - 1);
    const int l  = (idx >> 10) % Lq;
    const int s  = idx / (DI * Lq);
    const ushort_t* base = xz + (size_t)s * Lq * (2 * DI) + ch;  // xi_pre = cols [0,1024)
    const float4 wv = *(const float4*)(cw + ch * 4);
    float a = cb[ch];
    if (l >= 3) a += bf2f(base[(size_t)(l - 3) * (2 * DI)]) * wv.x;
    if (l >= 2) a += bf2f(base[(size_t)(l - 2) * (2 * DI)]) * wv.y;
    if (l >= 1) a += bf2f(base[(size_t)(l - 1) * (2 * DI)]) * wv.z;
    a += bf2f(base[(size_t)l * (2 * DI)]) * wv.w;
    const float sv = a / (1.0f + __expf(-a));
    xi[(size_t)(s * Lq + l) * DI + ch] = f2bf(sv);
}

// ---------------- sequential selective scan (y written in-place over xi) ----------------
__global__ void k_scan(const float* __restrict__ dt, const ushort_t* __restrict__ xz,
                       const ushort_t* __restrict__ xdbl, const float* __restrict__ A_log,
                       const float* __restrict__ Dp, ushort_t* __restrict__ xiy) {
    const int s  = blockIdx.x >> 4;                       // 40 sequences
    const int ch = ((blockIdx.x & 15) << 6) + threadIdx.x; // 1024 channels
    const float Av = -__expf(A_log[ch]);
    const float Dv = Dp[ch];
    const size_t tok0 = (size_t)s * Lq;
    const float*    pdt = dt  + tok0 * DI + ch;
    const ushort_t* pz  = xz  + tok0 * (2 * DI) + DI + ch;
    ushort_t*       pxi = xiy + tok0 * DI + ch;
    const ushort_t* pbc = xdbl + tok0 * XD_LD;

    float h = 0.0f;
    float dtv = pdt[0];
    float xiv = bf2f(pxi[0]);
    float zv  = bf2f(pz[0]);
    float bc  = bf2f(pbc[32]);
    float cc  = bf2f(pbc[33]);
    for (int l = 0; l < Lq; ++l) {
        float ndt = 0.f, nxi = 0.f, nz = 0.f, nbc = 0.f, ncc = 0.f;
        if (l + 1 < Lq) {
            const size_t o = (size_t)(l + 1);
            ndt = pdt[o * DI];
            nxi = bf2f(pxi[o * DI]);
            nz  = bf2f(pz[o * 2 * DI]);
            nbc = bf2f(pbc[o * XD_LD + 32]);
            ncc = bf2f(pbc[o * XD_LD + 33]);
        }
        const float dA = __expf(dtv * Av);
        h = dA * h + dtv * bc * xiv;
        float y = cc * h + Dv * xiv;
        y *= zv / (1.0f + __expf(-zv));
        pxi[(size_t)l * DI] = f2bf(y);
        dtv = ndt; xiv = nxi; zv = nz; bc = nbc; cc = ncc;
    }
}

// ---------------- 4-path gather + residual ----------------
__global__ void k_combine(const float* __restrict__ x, const ushort_t* __restrict__ ymm,
                          float* __restrict__ xr2) {
    const int tok  = blockIdx.x;
    const int lane = threadIdx.x;
    const int c0   = lane * 8;
    const int bi = tok / Lq;
    const int l1 = tok % Lq;
    const int t  = l1 / (Hh * Wd);
    const int hw = l1 % (Hh * Wd);
    const int hh = hw / Wd, ww = hw % Wd;
    const int l3 = (t * Wd + ww) * Hh + hh;
    union U { uint4 u; ushort_t h[8]; };
    U u0, u1, u2, u3;
    u0.u = *(const uint4*)(ymm + ((size_t)(0 * Bm + bi) * Lq + l1           ) * Dm + c0);
    u1.u = *(const uint4*)(ymm + ((size_t)(1 * Bm + bi) * Lq + (Lq - 1 - l1)) * Dm + c0);
    u2.u = *(const uint4*)(ymm + ((size_t)(2 * Bm + bi) * Lq + l3           ) * Dm + c0);
    u3.u = *(const uint4*)(ymm + ((size_t)(3 * Bm + bi) * Lq + (Lq - 1 - l3)) * Dm + c0);
    const float* px = x   + (size_t)tok * Dm + c0;
    float*       po = xr2 + (size_t)tok * Dm + c0;
#pragma unroll
    for (int j = 0; j < 8; ++j)
        po[j] = px[j] + bf2f(u0.h[j]) + bf2f(u1.h[j]) + bf2f(u2.h[j]) + bf2f(u3.h[j]);
}

// ---------------- LN2 ----------------
__global__ void k_ln2(const float* __restrict__ xin, const float* __restrict__ g,
                      const float* __restrict__ b, ushort_t* __restrict__ out) {
    const int tok  = blockIdx.x;
    const int lane = threadIdx.x;
    const int c0   = lane * 8;
    const float* row = xin + (size_t)tok * Dm;
    float4 v0 = *(const float4*)(row + c0);
    float4 v1 = *(const float4*)(row + c0 + 4);
    float s  = v0.x + v0.y + v0.z + v0.w + v1.x + v1.y + v1.z + v1.w;
    float ss = v0.x*v0.x + v0.y*v0.y + v0.z*v0.z + v0.w*v0.w
             + v1.x*v1.x + v1.y*v1.y + v1.z*v1.z + v1.w*v1.w;
#pragma unroll
    for (int o = 32; o >= 1; o >>= 1) { s += __shfl_xor(s, o); ss += __shfl_xor(ss, o); }
    const float mean = s * (1.0f / Dm);
    const float rstd = rsqrtf(ss * (1.0f / Dm) - mean * mean + 1e-5f);
    float4 g0 = *(const float4*)(g + c0), g1 = *(const float4*)(g + c0 + 4);
    float4 b0 = *(const float4*)(b + c0), b1 = *(const float4*)(b + c0 + 4);
    union { uint4 u; ushort_t h[8]; } pk;
    pk.h[0] = f2bf((v0.x - mean) * rstd * g0.x + b0.x);
    pk.h[1] = f2bf((v0.y - mean) * rstd * g0.y + b0.y);
    pk.h[2] = f2bf((v0.z - mean) * rstd * g0.z + b0.z);
    pk.h[3] = f2bf((v0.w - mean) * rstd * g0.w + b0.w);
    pk.h[4] = f2bf((v1.x - mean) * rstd * g1.x + b1.x);
    pk.h[5] = f2bf((v1.y - mean) * rstd * g1.y + b1.y);
    pk.h[6] = f2bf((v1.z - mean) * rstd * g1.z + b1.z);
    pk.h[7] = f2bf((v1.w - mean) * rstd * g1.w + b1.w);
    *(uint4*)(out + (size_t)tok * Dm + c0) = pk.u;
}

// ---------------- workspace layout ----------------
constexpr size_t SZ_CAT  = (size_t)MTOK * Dm * 2;        // also reused for ymm
constexpr size_t OFF_CAT = 0;
constexpr size_t OFF_XZ  = OFF_CAT + SZ_CAT;
constexpr size_t SZ_XZ   = (size_t)MTOK * 2 * DI * 2;
constexpr size_t OFF_XI  = OFF_XZ + SZ_XZ;
constexpr size_t SZ_XI   = (size_t)MTOK * DI * 2;
constexpr size_t OFF_XD  = OFF_XI + SZ_XI;
constexpr size_t SZ_XD   = (size_t)MTOK * XD_LD * 2;
constexpr size_t OFF_DT  = OFF_XD + SZ_XD;
constexpr size_t SZ_DT   = (size_t)MTOK * DI * 4;
constexpr size_t OFF_XR2 = OFF_DT;                        // dt dead after scan
constexpr size_t SZ_XR2  = (size_t)NTOK * Dm * 4;
constexpr size_t OFF_XL2 = OFF_XR2 + SZ_XR2;
constexpr size_t SZ_XL2  = (size_t)NTOK * Dm * 2;
constexpr size_t OFF_HM  = OFF_XL2 + SZ_XL2;
constexpr size_t SZ_HM   = (size_t)NTOK * 4 * Dm * 2;
constexpr size_t OFF_WIN = OFF_DT + SZ_DT;
constexpr size_t OFF_WOUT= OFF_WIN  + (size_t)2 * DI * Dm * 2;
constexpr size_t OFF_W1  = OFF_WOUT + (size_t)Dm * DI * 2;
constexpr size_t OFF_W2  = OFF_W1   + (size_t)4 * Dm * Dm * 2;
constexpr size_t OFF_WXP = OFF_W2   + (size_t)Dm * 4 * Dm * 2;
constexpr size_t OFF_WDT = OFF_WXP  + (size_t)(DR + 2) * DI * 2;
constexpr size_t WS_NEED = OFF_WDT  + (size_t)DI * DR * 2;
static_assert(OFF_HM + SZ_HM <= OFF_WIN, "xr2/xln2/hmid must fit inside dt region");

extern "C" void kernel_launch(void* const* d_in, const int* in_sizes, int n_in,
                              void* d_out, int out_size, void* d_ws, size_t ws_size,
                              hipStream_t stream) {
    const float* x        = (const float*)d_in[0];
    const float* ln1_g    = (const float*)d_in[1];
    const float* ln1_b    = (const float*)d_in[2];
    const float* ln2_g    = (const float*)d_in[3];
    const float* ln2_b    = (const float*)d_in[4];
    const float* mlp_w1   = (const float*)d_in[5];
    const float* mlp_b1   = (const float*)d_in[6];
    const float* mlp_w2   = (const float*)d_in[7];
    const float* mlp_b2   = (const float*)d_in[8];
    const float* in_w     = (const float*)d_in[9];
    const float* conv_w   = (const float*)d_in[10];
    const float* conv_b   = (const float*)d_in[11];
    const float* xproj_w  = (const float*)d_in[12];
    const float* dtproj_w = (const float*)d_in[13];
    const float* dtproj_b = (const float*)d_in[14];
    const float* A_log    = (const float*)d_in[15];
    const float* D_param  = (const float*)d_in[16];
    const float* out_w    = (const float*)d_in[17];

    if (ws_size < WS_NEED) return;  // loud failure (d_out stays zero)

    char* ws = (char*)d_ws;
    ushort_t* cat   = (ushort_t*)(ws + OFF_CAT);
    ushort_t* xz    = (ushort_t*)(ws + OFF_XZ);
    ushort_t* xi    = (ushort_t*)(ws + OFF_XI);
    ushort_t* xdbl  = (ushort_t*)(ws + OFF_XD);
    float*    dtb   = (float*)   (ws + OFF_DT);
    ushort_t* ymm   = (ushort_t*)(ws + OFF_CAT);  // reuse cat
    float*    xr2   = (float*)   (ws + OFF_XR2);
    ushort_t* xln2  = (ushort_t*)(ws + OFF_XL2);
    ushort_t* hmid  = (ushort_t*)(ws + OFF_HM);
    ushort_t* w_in  = (ushort_t*)(ws + OFF_WIN);
    ushort_t* w_out = (ushort_t*)(ws + OFF_WOUT);
    ushort_t* w_1   = (ushort_t*)(ws + OFF_W1);
    ushort_t* w_2   = (ushort_t*)(ws + OFF_W2);
    ushort_t* w_xp  = (ushort_t*)(ws + OFF_WXP);
    ushort_t* w_dt  = (ushort_t*)(ws + OFF_WDT);

    auto cvt = [&](const float* s, ushort_t* d, int n) {
        k_f2bf<<<(n + 255) / 256, 256, 0, stream>>>(s, d, n);
    };
    cvt(in_w,     w_in,  2 * DI * Dm);
    cvt(out_w,    w_out, Dm * DI);
    cvt(mlp_w1,   w_1,   4 * Dm * Dm);
    cvt(mlp_w2,   w_2,   Dm * 4 * Dm);
    cvt(xproj_w,  w_xp,  (DR + 2) * DI);
    cvt(dtproj_w, w_dt,  DI * DR);

    // LN1 + scatter into 4 scan paths
    k_ln1<<<NTOK, 64, 0, stream>>>(x, ln1_g, ln1_b, cat);

    // xz = cat @ in_w^T   (21120 x 2048, K=512)
    k_gemm_bt<0><<<dim3(MTOK / 64, (2 * DI) / 64), 256, 0, stream>>>(
        cat, w_in, xz, MTOK, 2 * DI, Dm, Dm, Dm, 2 * DI, nullptr, nullptr);

    // depthwise causal conv + SiLU -> xi
    k_conv<<<(MTOK * DI + 255) / 256, 256, 0, stream>>>(xz, conv_w, conv_b, xi);

    // x_dbl = xi @ xproj^T  (N=34, padded ld 40)
    k_gemm_bt<0><<<dim3(MTOK / 64, 1), 256, 0, stream>>>(
        xi, w_xp, xdbl, MTOK, DR + 2, DI, DI, DI, XD_LD, nullptr, nullptr);

    // dt = softplus(x_dbl[:, :32] @ dtproj^T + b)  (f32, K=32)
    k_gemm_bt<1><<<dim3(MTOK / 64, DI / 64), 256, 0, stream>>>(
        xdbl, w_dt, dtb, MTOK, DI, DR, XD_LD, DR, DI, dtproj_b, nullptr);

    // selective scan + gating; y in-place over xi
    k_scan<<<MBAT * 16, 64, 0, stream>>>(dtb, xz, xdbl, A_log, D_param, xi);

    // ymm = y @ out_w^T
    k_gemm_bt<0><<<dim3(MTOK / 64, Dm / 64), 256, 0, stream>>>(
        xi, w_out, ymm, MTOK, Dm, DI, DI, DI, Dm, nullptr, nullptr);

    // xr2 = x + y1 + flip(y2) + y3^T + flip(y4)^T
    k_combine<<<NTOK, 64, 0, stream>>>(x, ymm, xr2);

    // LN2
    k_ln2<<<NTOK, 64, 0, stream>>>(xr2, ln2_g, ln2_b, xln2);

    // hmid = gelu(xln2 @ w1^T + b1)
    k_gemm_bt<2><<<dim3((NTOK + 63) / 64, (4 * Dm) / 64), 256, 0, stream>>>(
        xln2, w_1, hmid, NTOK, 4 * Dm, Dm, Dm, Dm, 4 * Dm, mlp_b1, nullptr);

    // out = xr2 + hmid @ w2^T + b2  -> f32 d_out
    k_gemm_bt<3><<<dim3((NTOK + 63) / 64, Dm / 64), 256, 0, stream>>>(
        hmid, w_2, (float*)d_out, NTOK, Dm, 4 * Dm, 4 * Dm, 4 * Dm, Dm, mlp_b2, xr2);
}

// Round 4
// 510.677 us; speedup vs baseline: 1.2413x; 1.2413x over previous
//
#include <hip/hip_runtime.h>
#include <math.h>

typedef __attribute__((ext_vector_type(8))) short short8;   // 8 x bf16 bits
typedef __attribute__((ext_vector_type(8))) __bf16 bf16x8;  // MFMA operand type
typedef __attribute__((ext_vector_type(4))) float f32x4;
typedef unsigned short ushort_t;

#define DEV __device__ __forceinline__

// ---------------- problem constants ----------------
constexpr int Dm   = 512;
constexpr int DI   = 1024;
constexpr int DR   = 32;
constexpr int Hh   = 16;
constexpr int Wd   = 11;
constexpr int Bm   = 10;          // b * (Sf/T) = 2*5
constexpr int Lq   = 528;         // T*H*W
constexpr int NTOK = Bm * Lq;     // 5280
constexpr int MBAT = 4 * Bm;      // 40 (4 scan paths)
constexpr int MTOK = MBAT * Lq;   // 21120
constexpr int XD_LD = 40;         // padded ld for x_dbl (34 cols used)
constexpr int NCHK = 8;           // scan chunks per sequence
constexpr int CHK  = Lq / NCHK;   // 66
constexpr int MPAD = 5376;        // NTOK padded to multiple of 128

// ---------------- bf16 helpers (explicit RNE) ----------------
DEV ushort_t f2bf(float f) {
    unsigned u = __float_as_uint(f);
    u += 0x7fffu + ((u >> 16) & 1u);
    return (ushort_t)(u >> 16);
}
DEV float bf2f(ushort_t h) { return __uint_as_float(((unsigned)h) << 16); }

DEV bf16x8 as_bf(short8 v) { return __builtin_bit_cast(bf16x8, v); }

DEV void mfma_bf16(f32x4& d, short8 a, short8 b) {
    d = __builtin_amdgcn_mfma_f32_16x16x32_bf16(as_bf(a), as_bf(b), d, 0, 0, 0);
}

// async global->LDS, 16B per lane (dest = wave-uniform base + lane*16)
DEV void gll16(const ushort_t* g, ushort_t* l) {
    __builtin_amdgcn_global_load_lds((const __attribute__((address_space(1))) void*)g,
                                     (__attribute__((address_space(3))) void*)l,
                                     16, 0, 0);
}

// ---------------- f32 -> bf16 weight convert ----------------
__global__ void k_f2bf(const float* __restrict__ s, ushort_t* __restrict__ d, int n) {
    int i = blockIdx.x * 256 + threadIdx.x;
    if (i < n) d[i] = f2bf(s[i]);
}

// ---------------- LN1 + 4-path scatter into cat ----------------
__global__ void k_ln1(const float* __restrict__ x, const float* __restrict__ g,
                      const float* __restrict__ b, ushort_t* __restrict__ cat) {
    const int tok  = blockIdx.x;     // 0..NTOK-1, order = (b, t, h, w)
    const int lane = threadIdx.x;    // 64 threads
    const int c0   = lane * 8;
    const float* row = x + (size_t)tok * Dm;
    float4 v0 = *(const float4*)(row + c0);
    float4 v1 = *(const float4*)(row + c0 + 4);
    float s  = v0.x + v0.y + v0.z + v0.w + v1.x + v1.y + v1.z + v1.w;
    float ss = v0.x*v0.x + v0.y*v0.y + v0.z*v0.z + v0.w*v0.w
             + v1.x*v1.x + v1.y*v1.y + v1.z*v1.z + v1.w*v1.w;
#pragma unroll
    for (int o = 32; o >= 1; o >>= 1) { s += __shfl_xor(s, o); ss += __shfl_xor(ss, o); }
    const float mean = s * (1.0f / Dm);
    const float rstd = rsqrtf(ss * (1.0f / Dm) - mean * mean + 1e-5f);
    float4 g0 = *(const float4*)(g + c0), g1 = *(const float4*)(g + c0 + 4);
    float4 b0 = *(const float4*)(b + c0), b1 = *(const float4*)(b + c0 + 4);
    union { uint4 u; ushort_t h[8]; } pk;
    pk.h[0] = f2bf((v0.x - mean) * rstd * g0.x + b0.x);
    pk.h[1] = f2bf((v0.y - mean) * rstd * g0.y + b0.y);
    pk.h[2] = f2bf((v0.z - mean) * rstd * g0.z + b0.z);
    pk.h[3] = f2bf((v0.w - mean) * rstd * g0.w + b0.w);
    pk.h[4] = f2bf((v1.x - mean) * rstd * g1.x + b1.x);
    pk.h[5] = f2bf((v1.y - mean) * rstd * g1.y + b1.y);
    pk.h[6] = f2bf((v1.z - mean) * rstd * g1.z + b1.z);
    pk.h[7] = f2bf((v1.w - mean) * rstd * g1.w + b1.w);
    const int bi = tok / Lq;
    const int l1 = tok % Lq;                 // (t*H + h)*W + w
    const int t  = l1 / (Hh * Wd);
    const int hw = l1 % (Hh * Wd);
    const int hh = hw / Wd, ww = hw % Wd;
    const int l3 = (t * Wd + ww) * Hh + hh;  // (t*W + w)*H + h
    *(uint4*)(cat + ((size_t)(0 * Bm + bi) * Lq + l1           ) * Dm + c0) = pk.u;
    *(uint4*)(cat + ((size_t)(1 * Bm + bi) * Lq + (Lq - 1 - l1)) * Dm + c0) = pk.u;
    *(uint4*)(cat + ((size_t)(2 * Bm + bi) * Lq + l3           ) * Dm + c0) = pk.u;
    *(uint4*)(cat + ((size_t)(3 * Bm + bi) * Lq + (Lq - 1 - l3)) * Dm + c0) = pk.u;
}

// ---------------- m97-style 128-tile GEMM: C = A @ B^T ----------------
// Requires: grid.x*BM <= padded A rows, N % BN == 0, K % 64 == 0.
// Stores bounds-checked against M (real rows). EPI as in k_gemm_bt.
template<int BM, int BN, int EPI>
__launch_bounds__(256)
__global__ void k_gemm128(const ushort_t* __restrict__ A, const ushort_t* __restrict__ B,
                          void* __restrict__ C, int M, int N, int K,
                          int lda, int ldb, int ldc,
                          const float* __restrict__ bias, const float* __restrict__ resid) {
    constexpr int FM = BM / 32, FN = BN / 32;   // frags per wave (wave tile = BM/2 x BN/2)
    constexpr int AI = BM / 32, BI = BN / 32;   // global_load_lds instrs per wave
    __shared__ __align__(16) ushort_t As[BM * 64];
    __shared__ __align__(16) ushort_t Bs[BN * 64];
    const int tid  = threadIdx.x;
    const int lane = tid & 63;
    const int w    = tid >> 6;
    const int wm   = w >> 1, wn = w & 1;
    const int lr   = lane & 15, lg = lane >> 4;
    const int m0   = blockIdx.x * BM, n0 = blockIdx.y * BN;
    const int srow = lane >> 3;            // row-in-8 for staging
    const int scol = (lane & 7) * 8;       // col element for staging

    f32x4 acc[FM][FN] = {};

    for (int kb = 0; kb < K; kb += 64) {
#pragma unroll
        for (int i = 0; i < AI; ++i) {
            const int r = (w * AI + i) * 8 + srow;
            gll16(A + (size_t)(m0 + r) * lda + kb + scol, As + (w * AI + i) * 512 + lane * 8);
        }
#pragma unroll
        for (int i = 0; i < BI; ++i) {
            const int r = (w * BI + i) * 8 + srow;
            gll16(B + (size_t)(n0 + r) * ldb + kb + scol, Bs + (w * BI + i) * 512 + lane * 8);
        }
        __syncthreads();
#pragma unroll
        for (int kk = 0; kk < 2; ++kk) {
            short8 a[FM], b[FN];
#pragma unroll
            for (int mf = 0; mf < FM; ++mf)
                a[mf] = *(const short8*)(As + (size_t)(wm * (BM / 2) + mf * 16 + lr) * 64 + kk * 32 + lg * 8);
#pragma unroll
            for (int nf = 0; nf < FN; ++nf)
                b[nf] = *(const short8*)(Bs + (size_t)(wn * (BN / 2) + nf * 16 + lr) * 64 + kk * 32 + lg * 8);
#pragma unroll
            for (int mf = 0; mf < FM; ++mf)
#pragma unroll
                for (int nf = 0; nf < FN; ++nf)
                    mfma_bf16(acc[mf][nf], a[mf], b[nf]);
        }
        __syncthreads();
    }

#pragma unroll
    for (int mf = 0; mf < FM; ++mf)
#pragma unroll
        for (int nf = 0; nf < FN; ++nf) {
            const int gc = n0 + wn * (BN / 2) + nf * 16 + lr;
#pragma unroll
            for (int r = 0; r < 4; ++r) {
                const int gm = m0 + wm * (BM / 2) + mf * 16 + lg * 4 + r;
                if (gm >= M) continue;
                float v = acc[mf][nf][r];
                const size_t oi = (size_t)gm * ldc + gc;
                if constexpr (EPI == 0) {
                    ((ushort_t*)C)[oi] = f2bf(v);
                } else if constexpr (EPI == 2) {
                    v += bias[gc];
                    v = 0.5f * v * (1.0f + erff(v * 0.70710678118654752f));
                    ((ushort_t*)C)[oi] = f2bf(v);
                } else if constexpr (EPI == 3) {
                    v += bias[gc] + resid[oi];
                    ((float*)C)[oi] = v;   // d_out is float32
                }
            }
        }
}

// ---------------- generic 64-tile GEMM (handles ragged N / K<64) ----------------
// EPI 0: bf16 store | 1: softplus(acc+bias) bf16
template<int EPI>
__launch_bounds__(256)
__global__ void k_gemm_bt(const ushort_t* __restrict__ A, const ushort_t* __restrict__ B,
                          void* __restrict__ C, int M, int N, int K,
                          int lda, int ldb, int ldc,
                          const float* __restrict__ bias) {
    constexpr int BM = 64, BN = 64, BK = 64, LDL = BK + 8;
    __shared__ __align__(16) ushort_t As[BM][LDL];
    __shared__ __align__(16) ushort_t Bs[BN][LDL];
    const int tid  = threadIdx.x;
    const int m0   = blockIdx.x * BM, n0 = blockIdx.y * BN;
    const int lane = tid & 63;
    const int wv   = tid >> 6;
    const int wm   = wv >> 1, wn = wv & 1;
    const int lr   = lane & 15, lg = lane >> 4;

    f32x4 acc[2][2] = {};

    for (int kb = 0; kb < K; kb += BK) {
#pragma unroll
        for (int j = 0; j < 2; ++j) {
            const int chunk = tid + j * 256;
            const int row = chunk >> 3;
            const int k0  = (chunk & 7) << 3;
            const int gk  = kb + k0;
            short8 va = {};
            const int gm = m0 + row;
            if (gm < M && gk < K) va = *(const short8*)(A + (size_t)gm * lda + gk);
            *(short8*)(&As[row][k0]) = va;
            short8 vb = {};
            const int gn = n0 + row;
            if (gn < N && gk < K) vb = *(const short8*)(B + (size_t)gn * ldb + gk);
            *(short8*)(&Bs[row][k0]) = vb;
        }
        __syncthreads();
#pragma unroll
        for (int kk = 0; kk < 2; ++kk) {
            short8 a0 = *(const short8*)(&As[wm * 32 +  0 + lr][kk * 32 + lg * 8]);
            short8 a1 = *(const short8*)(&As[wm * 32 + 16 + lr][kk * 32 + lg * 8]);
            short8 b0 = *(const short8*)(&Bs[wn * 32 +  0 + lr][kk * 32 + lg * 8]);
            short8 b1 = *(const short8*)(&Bs[wn * 32 + 16 + lr][kk * 32 + lg * 8]);
            mfma_bf16(acc[0][0], a0, b0);
            mfma_bf16(acc[0][1], a0, b1);
            mfma_bf16(acc[1][0], a1, b0);
            mfma_bf16(acc[1][1], a1, b1);
        }
        __syncthreads();
    }

#pragma unroll
    for (int mf = 0; mf < 2; ++mf)
#pragma unroll
        for (int nf = 0; nf < 2; ++nf) {
            const int gc = n0 + wn * 32 + nf * 16 + lr;
            if (gc >= N) continue;
#pragma unroll
            for (int r = 0; r < 4; ++r) {
                const int gm = m0 + wm * 32 + mf * 16 + lg * 4 + r;
                if (gm >= M) continue;
                float v = acc[mf][nf][r];
                const size_t oi = (size_t)gm * ldc + gc;
                if constexpr (EPI == 0) {
                    ((ushort_t*)C)[oi] = f2bf(v);
                } else {
                    v += bias[gc];
                    v = (v > 20.0f) ? v : log1pf(__expf(v));
                    ((ushort_t*)C)[oi] = f2bf(v);
                }
            }
        }
}

// ---------------- depthwise causal conv (DC=4) + SiLU ----------------
__global__ void k_conv(const ushort_t* __restrict__ xz, const float* __restrict__ cw,
                       const float* __restrict__ cb, ushort_t* __restrict__ xi) {
    const int idx = blockIdx.x * 256 + threadIdx.x;
    if (idx >= MTOK * DI) return;
    const int ch = idx & (DI - 1);
    const int l  = (idx >> 10) % Lq;
    const int s  = idx / (DI * Lq);
    const ushort_t* base = xz + (size_t)s * Lq * (2 * DI) + ch;
    const float4 wv = *(const float4*)(cw + ch * 4);
    float a = cb[ch];
    if (l >= 3) a += bf2f(base[(size_t)(l - 3) * (2 * DI)]) * wv.x;
    if (l >= 2) a += bf2f(base[(size_t)(l - 2) * (2 * DI)]) * wv.y;
    if (l >= 1) a += bf2f(base[(size_t)(l - 1) * (2 * DI)]) * wv.z;
    a += bf2f(base[(size_t)l * (2 * DI)]) * wv.w;
    const float sv = a / (1.0f + __expf(-a));
    xi[(size_t)(s * Lq + l) * DI + ch] = f2bf(sv);
}

// ---------------- chunked selective scan ----------------
// phase 1: per (seq, chunk, ch): local scan with h0=0.
//   y_loc = (Cc*h_loc + D*xi)*silu(z)   (in-place over xi)
//   corr  = Cc * prefixprod(dA) * silu(z)
//   P = prod(dA), S = h_loc at chunk end
__global__ void k_scan1(const ushort_t* __restrict__ dt, const ushort_t* __restrict__ xz,
                        const ushort_t* __restrict__ xdbl, const float* __restrict__ A_log,
                        const float* __restrict__ Dp, ushort_t* __restrict__ xiy,
                        ushort_t* __restrict__ corr, float* __restrict__ Pb,
                        float* __restrict__ Sb) {
    const int blk = blockIdx.x;                    // s*128 + j*16 + cg
    const int s  = blk >> 7;
    const int j  = (blk >> 4) & 7;
    const int ch = ((blk & 15) << 6) + threadIdx.x;
    const float Av = -__expf(A_log[ch]);
    const float Dv = Dp[ch];
    const size_t tok0 = (size_t)s * Lq + (size_t)j * CHK;
    const ushort_t* pdt = dt  + tok0 * DI + ch;
    const ushort_t* pz  = xz  + tok0 * (2 * DI) + DI + ch;
    ushort_t*       pxi = xiy + tok0 * DI + ch;
    ushort_t*       pco = corr + tok0 * DI + ch;
    const ushort_t* pbc = xdbl + tok0 * XD_LD;

    float h = 0.0f, pp = 1.0f;
    float dtv = bf2f(pdt[0]);
    float xiv = bf2f(pxi[0]);
    float zv  = bf2f(pz[0]);
    float bc  = bf2f(pbc[32]);
    float cc  = bf2f(pbc[33]);
    for (int l = 0; l < CHK; ++l) {
        float ndt = 0.f, nxi = 0.f, nz = 0.f, nbc = 0.f, ncc = 0.f;
        if (l + 1 < CHK) {
            const size_t o = (size_t)(l + 1);
            ndt = bf2f(pdt[o * DI]);
            nxi = bf2f(pxi[o * DI]);
            nz  = bf2f(pz[o * 2 * DI]);
            nbc = bf2f(pbc[o * XD_LD + 32]);
            ncc = bf2f(pbc[o * XD_LD + 33]);
        }
        const float dA = __expf(dtv * Av);
        h = dA * h + dtv * bc * xiv;
        pp *= dA;
        const float sz = zv / (1.0f + __expf(-zv));
        pxi[(size_t)l * DI] = f2bf((cc * h + Dv * xiv) * sz);
        pco[(size_t)l * DI] = f2bf(cc * pp * sz);
        dtv = ndt; xiv = nxi; zv = nz; bc = nbc; cc = ncc;
    }
    const size_t pi = (size_t)(s * NCHK + j) * DI + ch;
    Pb[pi] = pp;
    Sb[pi] = h;
}

// phase 2: carries c_j per (seq, ch): c_0 = 0; c_{j+1} = P_j*c_j + S_j
__global__ void k_scan2(const float* __restrict__ Pb, const float* __restrict__ Sb,
                        float* __restrict__ cb) {
    const int s  = blockIdx.x >> 4;
    const int ch = ((blockIdx.x & 15) << 6) + threadIdx.x;
    float c = 0.0f;
#pragma unroll
    for (int j = 0; j < NCHK; ++j) {
        const size_t pi = (size_t)(s * NCHK + j) * DI + ch;
        cb[pi] = c;
        c = Pb[pi] * c + Sb[pi];
    }
}

// phase 3: y = y_loc + c * corr (vectorized x8)
__global__ void k_scan3(ushort_t* __restrict__ y, const ushort_t* __restrict__ corr,
                        const float* __restrict__ cb) {
    const int idx = blockIdx.x * 256 + threadIdx.x;   // MTOK*DI/8 total
    const int tok = idx >> 7;                         // DI/8 = 128 groups per token
    const int ch0 = (idx & 127) << 3;
    const int s   = tok / Lq;
    const int j   = (tok % Lq) / CHK;
    const size_t off = (size_t)tok * DI + ch0;
    union U { uint4 u; ushort_t h[8]; };
    U yv, cv, ov;
    yv.u = *(const uint4*)(y + off);
    cv.u = *(const uint4*)(corr + off);
    const float* cp = cb + (size_t)(s * NCHK + j) * DI + ch0;
    float4 c0 = *(const float4*)(cp);
    float4 c1 = *(const float4*)(cp + 4);
    ov.h[0] = f2bf(bf2f(yv.h[0]) + c0.x * bf2f(cv.h[0]));
    ov.h[1] = f2bf(bf2f(yv.h[1]) + c0.y * bf2f(cv.h[1]));
    ov.h[2] = f2bf(bf2f(yv.h[2]) + c0.z * bf2f(cv.h[2]));
    ov.h[3] = f2bf(bf2f(yv.h[3]) + c0.w * bf2f(cv.h[3]));
    ov.h[4] = f2bf(bf2f(yv.h[4]) + c1.x * bf2f(cv.h[4]));
    ov.h[5] = f2bf(bf2f(yv.h[5]) + c1.y * bf2f(cv.h[5]));
    ov.h[6] = f2bf(bf2f(yv.h[6]) + c1.z * bf2f(cv.h[6]));
    ov.h[7] = f2bf(bf2f(yv.h[7]) + c1.w * bf2f(cv.h[7]));
    *(uint4*)(y + off) = ov.u;
}

// ---------------- 4-path gather + residual ----------------
__global__ void k_combine(const float* __restrict__ x, const ushort_t* __restrict__ ymm,
                          float* __restrict__ xr2) {
    const int tok  = blockIdx.x;
    const int lane = threadIdx.x;
    const int c0   = lane * 8;
    const int bi = tok / Lq;
    const int l1 = tok % Lq;
    const int t  = l1 / (Hh * Wd);
    const int hw = l1 % (Hh * Wd);
    const int hh = hw / Wd, ww = hw % Wd;
    const int l3 = (t * Wd + ww) * Hh + hh;
    union U { uint4 u; ushort_t h[8]; };
    U u0, u1, u2, u3;
    u0.u = *(const uint4*)(ymm + ((size_t)(0 * Bm + bi) * Lq + l1           ) * Dm + c0);
    u1.u = *(const uint4*)(ymm + ((size_t)(1 * Bm + bi) * Lq + (Lq - 1 - l1)) * Dm + c0);
    u2.u = *(const uint4*)(ymm + ((size_t)(2 * Bm + bi) * Lq + l3           ) * Dm + c0);
    u3.u = *(const uint4*)(ymm + ((size_t)(3 * Bm + bi) * Lq + (Lq - 1 - l3)) * Dm + c0);
    const float* px = x   + (size_t)tok * Dm + c0;
    float*       po = xr2 + (size_t)tok * Dm + c0;
#pragma unroll
    for (int j = 0; j < 8; ++j)
        po[j] = px[j] + bf2f(u0.h[j]) + bf2f(u1.h[j]) + bf2f(u2.h[j]) + bf2f(u3.h[j]);
}

// ---------------- LN2 ----------------
__global__ void k_ln2(const float* __restrict__ xin, const float* __restrict__ g,
                      const float* __restrict__ b, ushort_t* __restrict__ out) {
    const int tok  = blockIdx.x;
    const int lane = threadIdx.x;
    const int c0   = lane * 8;
    const float* row = xin + (size_t)tok * Dm;
    float4 v0 = *(const float4*)(row + c0);
    float4 v1 = *(const float4*)(row + c0 + 4);
    float s  = v0.x + v0.y + v0.z + v0.w + v1.x + v1.y + v1.z + v1.w;
    float ss = v0.x*v0.x + v0.y*v0.y + v0.z*v0.z + v0.w*v0.w
             + v1.x*v1.x + v1.y*v1.y + v1.z*v1.z + v1.w*v1.w;
#pragma unroll
    for (int o = 32; o >= 1; o >>= 1) { s += __shfl_xor(s, o); ss += __shfl_xor(ss, o); }
    const float mean = s * (1.0f / Dm);
    const float rstd = rsqrtf(ss * (1.0f / Dm) - mean * mean + 1e-5f);
    float4 g0 = *(const float4*)(g + c0), g1 = *(const float4*)(g + c0 + 4);
    float4 b0 = *(const float4*)(b + c0), b1 = *(const float4*)(b + c0 + 4);
    union { uint4 u; ushort_t h[8]; } pk;
    pk.h[0] = f2bf((v0.x - mean) * rstd * g0.x + b0.x);
    pk.h[1] = f2bf((v0.y - mean) * rstd * g0.y + b0.y);
    pk.h[2] = f2bf((v0.z - mean) * rstd * g0.z + b0.z);
    pk.h[3] = f2bf((v0.w - mean) * rstd * g0.w + b0.w);
    pk.h[4] = f2bf((v1.x - mean) * rstd * g1.x + b1.x);
    pk.h[5] = f2bf((v1.y - mean) * rstd * g1.y + b1.y);
    pk.h[6] = f2bf((v1.z - mean) * rstd * g1.z + b1.z);
    pk.h[7] = f2bf((v1.w - mean) * rstd * g1.w + b1.w);
    *(uint4*)(out + (size_t)tok * Dm + c0) = pk.u;
}

// ---------------- workspace layout ----------------
constexpr size_t SZ_CAT  = (size_t)MTOK * Dm * 2;        // reused: P/S/c (scan), then ymm
constexpr size_t OFF_CAT = 0;
constexpr size_t OFF_XZ  = OFF_CAT + SZ_CAT;
constexpr size_t SZ_XZ   = (size_t)MTOK * 2 * DI * 2;
constexpr size_t OFF_XI  = OFF_XZ + SZ_XZ;
constexpr size_t SZ_XI   = (size_t)MTOK * DI * 2;
constexpr size_t OFF_XD  = OFF_XI + SZ_XI;
constexpr size_t SZ_XD   = (size_t)MTOK * XD_LD * 2;
constexpr size_t OFF_DT  = OFF_XD + SZ_XD;               // dt bf16
constexpr size_t SZ_DT   = (size_t)MTOK * DI * 2;
constexpr size_t OFF_CO  = OFF_DT + SZ_DT;               // corr bf16
constexpr size_t SZ_CO   = (size_t)MTOK * DI * 2;
// after scan, dt+corr region is reused for xr2 / xln2 / hmid
constexpr size_t OFF_XR2 = OFF_DT;
constexpr size_t SZ_XR2  = (size_t)NTOK * Dm * 4;
constexpr size_t OFF_XL2 = OFF_XR2 + SZ_XR2;
constexpr size_t SZ_XL2  = (size_t)MPAD * Dm * 2;
constexpr size_t OFF_HM  = OFF_XL2 + SZ_XL2;
constexpr size_t SZ_HM   = (size_t)MPAD * 4 * Dm * 2;
// P/S/c live inside the (dead-after-inproj) cat region
constexpr size_t SZ_PSC  = (size_t)MBAT * NCHK * DI * 4; // 1.31 MB each
constexpr size_t OFF_P   = OFF_CAT;
constexpr size_t OFF_S   = OFF_P + SZ_PSC;
constexpr size_t OFF_C   = OFF_S + SZ_PSC;
constexpr size_t OFF_WIN = OFF_CO + SZ_CO;
constexpr size_t OFF_WOUT= OFF_WIN  + (size_t)2 * DI * Dm * 2;
constexpr size_t OFF_W1  = OFF_WOUT + (size_t)Dm * DI * 2;
constexpr size_t OFF_W2  = OFF_W1   + (size_t)4 * Dm * Dm * 2;
constexpr size_t OFF_WXP = OFF_W2   + (size_t)Dm * 4 * Dm * 2;
constexpr size_t OFF_WDT = OFF_WXP  + (size_t)(DR + 2) * DI * 2;
constexpr size_t WS_NEED = OFF_WDT  + (size_t)DI * DR * 2;
static_assert(OFF_HM + SZ_HM <= OFF_WIN, "xr2/xln2/hmid must fit inside dt+corr region");
static_assert(OFF_C + SZ_PSC <= OFF_CAT + SZ_CAT, "P/S/c must fit inside cat region");

extern "C" void kernel_launch(void* const* d_in, const int* in_sizes, int n_in,
                              void* d_out, int out_size, void* d_ws, size_t ws_size,
                              hipStream_t stream) {
    const float* x        = (const float*)d_in[0];
    const float* ln1_g    = (const float*)d_in[1];
    const float* ln1_b    = (const float*)d_in[2];
    const float* ln2_g    = (const float*)d_in[3];
    const float* ln2_b    = (const float*)d_in[4];
    const float* mlp_w1   = (const float*)d_in[5];
    const float* mlp_b1   = (const float*)d_in[6];
    const float* mlp_w2   = (const float*)d_in[7];
    const float* mlp_b2   = (const float*)d_in[8];
    const float* in_w     = (const float*)d_in[9];
    const float* conv_w   = (const float*)d_in[10];
    const float* conv_b   = (const float*)d_in[11];
    const float* xproj_w  = (const float*)d_in[12];
    const float* dtproj_w = (const float*)d_in[13];
    const float* dtproj_b = (const float*)d_in[14];
    const float* A_log    = (const float*)d_in[15];
    const float* D_param  = (const float*)d_in[16];
    const float* out_w    = (const float*)d_in[17];

    if (ws_size < WS_NEED) return;  // loud failure (d_out stays zero)

    char* ws = (char*)d_ws;
    ushort_t* cat   = (ushort_t*)(ws + OFF_CAT);
    ushort_t* xz    = (ushort_t*)(ws + OFF_XZ);
    ushort_t* xi    = (ushort_t*)(ws + OFF_XI);
    ushort_t* xdbl  = (ushort_t*)(ws + OFF_XD);
    ushort_t* dtb   = (ushort_t*)(ws + OFF_DT);
    ushort_t* corr  = (ushort_t*)(ws + OFF_CO);
    float*    Pb    = (float*)   (ws + OFF_P);
    float*    Sb    = (float*)   (ws + OFF_S);
    float*    cb    = (float*)   (ws + OFF_C);
    ushort_t* ymm   = (ushort_t*)(ws + OFF_CAT);  // reuse cat (after P/S/c dead)
    float*    xr2   = (float*)   (ws + OFF_XR2);
    ushort_t* xln2  = (ushort_t*)(ws + OFF_XL2);
    ushort_t* hmid  = (ushort_t*)(ws + OFF_HM);
    ushort_t* w_in  = (ushort_t*)(ws + OFF_WIN);
    ushort_t* w_out = (ushort_t*)(ws + OFF_WOUT);
    ushort_t* w_1   = (ushort_t*)(ws + OFF_W1);
    ushort_t* w_2   = (ushort_t*)(ws + OFF_W2);
    ushort_t* w_xp  = (ushort_t*)(ws + OFF_WXP);
    ushort_t* w_dt  = (ushort_t*)(ws + OFF_WDT);

    auto cvt = [&](const float* s, ushort_t* d, int n) {
        k_f2bf<<<(n + 255) / 256, 256, 0, stream>>>(s, d, n);
    };
    cvt(in_w,     w_in,  2 * DI * Dm);
    cvt(out_w,    w_out, Dm * DI);
    cvt(mlp_w1,   w_1,   4 * Dm * Dm);
    cvt(mlp_w2,   w_2,   Dm * 4 * Dm);
    cvt(xproj_w,  w_xp,  (DR + 2) * DI);
    cvt(dtproj_w, w_dt,  DI * DR);

    // LN1 + scatter into 4 scan paths
    k_ln1<<<NTOK, 64, 0, stream>>>(x, ln1_g, ln1_b, cat);

    // xz = cat @ in_w^T   (21120 x 2048, K=512)
    k_gemm128<128, 128, 0><<<dim3(MTOK / 128, (2 * DI) / 128), 256, 0, stream>>>(
        cat, w_in, xz, MTOK, 2 * DI, Dm, Dm, Dm, 2 * DI, nullptr, nullptr);

    // depthwise causal conv + SiLU -> xi
    k_conv<<<(MTOK * DI + 255) / 256, 256, 0, stream>>>(xz, conv_w, conv_b, xi);

    // x_dbl = xi @ xproj^T  (N=34, padded ld 40)
    k_gemm_bt<0><<<dim3(MTOK / 64, 1), 256, 0, stream>>>(
        xi, w_xp, xdbl, MTOK, DR + 2, DI, DI, DI, XD_LD, nullptr);

    // dt = softplus(x_dbl[:, :32] @ dtproj^T + b)  (bf16, K=32)
    k_gemm_bt<1><<<dim3(MTOK / 64, DI / 64), 256, 0, stream>>>(
        xdbl, w_dt, dtb, MTOK, DI, DR, XD_LD, DR, DI, dtproj_b);

    // chunked selective scan
    k_scan1<<<MBAT * NCHK * 16, 64, 0, stream>>>(dtb, xz, xdbl, A_log, D_param,
                                                 xi, corr, Pb, Sb);
    k_scan2<<<MBAT * 16, 64, 0, stream>>>(Pb, Sb, cb);
    k_scan3<<<(MTOK * DI / 8) / 256, 256, 0, stream>>>(xi, corr, cb);

    // ymm = y @ out_w^T
    k_gemm128<128, 128, 0><<<dim3(MTOK / 128, Dm / 128), 256, 0, stream>>>(
        xi, w_out, ymm, MTOK, Dm, DI, DI, DI, Dm, nullptr, nullptr);

    // xr2 = x + y1 + flip(y2) + y3^T + flip(y4)^T
    k_combine<<<NTOK, 64, 0, stream>>>(x, ymm, xr2);

    // LN2
    k_ln2<<<NTOK, 64, 0, stream>>>(xr2, ln2_g, ln2_b, xln2);

    // hmid = gelu(xln2 @ w1^T + b1)   (M padded to 5376 for staging)
    k_gemm128<128, 128, 2><<<dim3(MPAD / 128, (4 * Dm) / 128), 256, 0, stream>>>(
        xln2, w_1, hmid, NTOK, 4 * Dm, Dm, Dm, Dm, 4 * Dm, mlp_b1, nullptr);

    // out = xr2 + hmid @ w2^T + b2  -> f32 d_out
    k_gemm128<128, 64, 3><<<dim3(MPAD / 128, Dm / 64), 256, 0, stream>>>(
        hmid, w_2, (float*)d_out, NTOK, Dm, 4 * Dm, 4 * Dm, 4 * Dm, Dm, mlp_b2, xr2);
}

// Round 5
// 442.385 us; speedup vs baseline: 1.4329x; 1.1544x over previous
//
#include <hip/hip_runtime.h>
#include <math.h>

typedef __attribute__((ext_vector_type(8))) short short8;   // 8 x bf16 bits
typedef __attribute__((ext_vector_type(8))) __bf16 bf16x8;  // MFMA operand type
typedef __attribute__((ext_vector_type(4))) float f32x4;
typedef unsigned short ushort_t;

#define DEV __device__ __forceinline__

// ---------------- problem constants ----------------
constexpr int Dm   = 512;
constexpr int DI   = 1024;
constexpr int DR   = 32;
constexpr int Hh   = 16;
constexpr int Wd   = 11;
constexpr int Bm   = 10;          // b * (Sf/T) = 2*5
constexpr int Lq   = 528;         // T*H*W
constexpr int NTOK = Bm * Lq;     // 5280
constexpr int MBAT = 4 * Bm;      // 40 (4 scan paths)
constexpr int MTOK = MBAT * Lq;   // 21120
constexpr int XD_LD = 40;         // padded ld for x_dbl (34 cols used)
constexpr int NCHK = 8;           // scan chunks per sequence
constexpr int CHK  = Lq / NCHK;   // 66
constexpr int MPAD = 5376;        // NTOK padded to multiple of 128

// ---------------- bf16 helpers (explicit RNE) ----------------
DEV ushort_t f2bf(float f) {
    unsigned u = __float_as_uint(f);
    u += 0x7fffu + ((u >> 16) & 1u);
    return (ushort_t)(u >> 16);
}
DEV float bf2f(ushort_t h) { return __uint_as_float(((unsigned)h) << 16); }

DEV bf16x8 as_bf(short8 v) { return __builtin_bit_cast(bf16x8, v); }

DEV void mfma_bf16(f32x4& d, short8 a, short8 b) {
    d = __builtin_amdgcn_mfma_f32_16x16x32_bf16(as_bf(a), as_bf(b), d, 0, 0, 0);
}

// async global->LDS, 16B per lane (dest = wave-uniform base + lane*16)
DEV void gll16(const ushort_t* g, ushort_t* l) {
    __builtin_amdgcn_global_load_lds((const __attribute__((address_space(1))) void*)g,
                                     (__attribute__((address_space(3))) void*)l,
                                     16, 0, 0);
}

// path-local index q (in path p's scan order) -> global token index (bi*Lq + l1)
DEV int path_tok(int p, int bi, int q) {
    int ql = (p & 1) ? (Lq - 1 - q) : q;   // paths 1,3 are flipped
    int l1;
    if (p < 2) {
        l1 = ql;
    } else {                               // path 2/3: q encodes (t*Wd+ww)*Hh+hh
        int t   = ql / (Hh * Wd);
        int rem = ql - t * (Hh * Wd);
        int ww  = rem / Hh;
        int hh  = rem - ww * Hh;
        l1 = (t * Hh + hh) * Wd + ww;
    }
    return bi * Lq + l1;
}

// ---------------- f32 -> bf16 weight convert ----------------
__global__ void k_f2bf(const float* __restrict__ s, ushort_t* __restrict__ d, int n) {
    int i = blockIdx.x * 256 + threadIdx.x;
    if (i < n) d[i] = f2bf(s[i]);
}

// ---------------- LN1 (single row per token, no scatter) ----------------
__global__ void k_ln1(const float* __restrict__ x, const float* __restrict__ g,
                      const float* __restrict__ b, ushort_t* __restrict__ xn) {
    const int tok  = blockIdx.x;     // 0..NTOK-1
    const int lane = threadIdx.x;    // 64 threads
    const int c0   = lane * 8;
    const float* row = x + (size_t)tok * Dm;
    float4 v0 = *(const float4*)(row + c0);
    float4 v1 = *(const float4*)(row + c0 + 4);
    float s  = v0.x + v0.y + v0.z + v0.w + v1.x + v1.y + v1.z + v1.w;
    float ss = v0.x*v0.x + v0.y*v0.y + v0.z*v0.z + v0.w*v0.w
             + v1.x*v1.x + v1.y*v1.y + v1.z*v1.z + v1.w*v1.w;
#pragma unroll
    for (int o = 32; o >= 1; o >>= 1) { s += __shfl_xor(s, o); ss += __shfl_xor(ss, o); }
    const float mean = s * (1.0f / Dm);
    const float rstd = rsqrtf(ss * (1.0f / Dm) - mean * mean + 1e-5f);
    float4 g0 = *(const float4*)(g + c0), g1 = *(const float4*)(g + c0 + 4);
    float4 b0 = *(const float4*)(b + c0), b1 = *(const float4*)(b + c0 + 4);
    union { uint4 u; ushort_t h[8]; } pk;
    pk.h[0] = f2bf((v0.x - mean) * rstd * g0.x + b0.x);
    pk.h[1] = f2bf((v0.y - mean) * rstd * g0.y + b0.y);
    pk.h[2] = f2bf((v0.z - mean) * rstd * g0.z + b0.z);
    pk.h[3] = f2bf((v0.w - mean) * rstd * g0.w + b0.w);
    pk.h[4] = f2bf((v1.x - mean) * rstd * g1.x + b1.x);
    pk.h[5] = f2bf((v1.y - mean) * rstd * g1.y + b1.y);
    pk.h[6] = f2bf((v1.z - mean) * rstd * g1.z + b1.z);
    pk.h[7] = f2bf((v1.w - mean) * rstd * g1.w + b1.w);
    *(uint4*)(xn + (size_t)tok * Dm + c0) = pk.u;
}

// ---------------- m97-style 128-tile GEMM: C = A @ B^T ----------------
// EPI 0: bf16 | 2: gelu(acc+bias) bf16 | 3: acc+bias+resid f32 | 4: acc+resid f32
template<int BM, int BN, int EPI>
__launch_bounds__(256)
__global__ void k_gemm128(const ushort_t* __restrict__ A, const ushort_t* __restrict__ B,
                          void* __restrict__ C, int M, int N, int K,
                          int lda, int ldb, int ldc,
                          const float* __restrict__ bias, const float* __restrict__ resid) {
    constexpr int FM = BM / 32, FN = BN / 32;
    constexpr int AI = BM / 32, BI = BN / 32;
    __shared__ __align__(16) ushort_t As[BM * 64];
    __shared__ __align__(16) ushort_t Bs[BN * 64];
    const int tid  = threadIdx.x;
    const int lane = tid & 63;
    const int w    = tid >> 6;
    const int wm   = w >> 1, wn = w & 1;
    const int lr   = lane & 15, lg = lane >> 4;
    const int m0   = blockIdx.x * BM, n0 = blockIdx.y * BN;
    const int srow = lane >> 3;
    const int scol = (lane & 7) * 8;

    f32x4 acc[FM][FN] = {};

    for (int kb = 0; kb < K; kb += 64) {
#pragma unroll
        for (int i = 0; i < AI; ++i) {
            const int r = (w * AI + i) * 8 + srow;
            gll16(A + (size_t)(m0 + r) * lda + kb + scol, As + (w * AI + i) * 512 + lane * 8);
        }
#pragma unroll
        for (int i = 0; i < BI; ++i) {
            const int r = (w * BI + i) * 8 + srow;
            gll16(B + (size_t)(n0 + r) * ldb + kb + scol, Bs + (w * BI + i) * 512 + lane * 8);
        }
        __syncthreads();
#pragma unroll
        for (int kk = 0; kk < 2; ++kk) {
            short8 a[FM], b[FN];
#pragma unroll
            for (int mf = 0; mf < FM; ++mf)
                a[mf] = *(const short8*)(As + (size_t)(wm * (BM / 2) + mf * 16 + lr) * 64 + kk * 32 + lg * 8);
#pragma unroll
            for (int nf = 0; nf < FN; ++nf)
                b[nf] = *(const short8*)(Bs + (size_t)(wn * (BN / 2) + nf * 16 + lr) * 64 + kk * 32 + lg * 8);
#pragma unroll
            for (int mf = 0; mf < FM; ++mf)
#pragma unroll
                for (int nf = 0; nf < FN; ++nf)
                    mfma_bf16(acc[mf][nf], a[mf], b[nf]);
        }
        __syncthreads();
    }

#pragma unroll
    for (int mf = 0; mf < FM; ++mf)
#pragma unroll
        for (int nf = 0; nf < FN; ++nf) {
            const int gc = n0 + wn * (BN / 2) + nf * 16 + lr;
#pragma unroll
            for (int r = 0; r < 4; ++r) {
                const int gm = m0 + wm * (BM / 2) + mf * 16 + lg * 4 + r;
                if (gm >= M) continue;
                float v = acc[mf][nf][r];
                const size_t oi = (size_t)gm * ldc + gc;
                if constexpr (EPI == 0) {
                    ((ushort_t*)C)[oi] = f2bf(v);
                } else if constexpr (EPI == 2) {
                    v += bias[gc];
                    v = 0.5f * v * (1.0f + erff(v * 0.70710678118654752f));
                    ((ushort_t*)C)[oi] = f2bf(v);
                } else if constexpr (EPI == 3) {
                    v += bias[gc] + resid[oi];
                    ((float*)C)[oi] = v;
                } else if constexpr (EPI == 4) {
                    v += resid[oi];
                    ((float*)C)[oi] = v;
                }
            }
        }
}

// ---------------- generic 64-tile GEMM (ragged N / K<64) ----------------
// EPI 0: bf16 store | 1: softplus(acc+bias) bf16
template<int EPI>
__launch_bounds__(256)
__global__ void k_gemm_bt(const ushort_t* __restrict__ A, const ushort_t* __restrict__ B,
                          void* __restrict__ C, int M, int N, int K,
                          int lda, int ldb, int ldc,
                          const float* __restrict__ bias) {
    constexpr int BM = 64, BN = 64, BK = 64, LDL = BK + 8;
    __shared__ __align__(16) ushort_t As[BM][LDL];
    __shared__ __align__(16) ushort_t Bs[BN][LDL];
    const int tid  = threadIdx.x;
    const int m0   = blockIdx.x * BM, n0 = blockIdx.y * BN;
    const int lane = tid & 63;
    const int wv   = tid >> 6;
    const int wm   = wv >> 1, wn = wv & 1;
    const int lr   = lane & 15, lg = lane >> 4;

    f32x4 acc[2][2] = {};

    for (int kb = 0; kb < K; kb += BK) {
#pragma unroll
        for (int j = 0; j < 2; ++j) {
            const int chunk = tid + j * 256;
            const int row = chunk >> 3;
            const int k0  = (chunk & 7) << 3;
            const int gk  = kb + k0;
            short8 va = {};
            const int gm = m0 + row;
            if (gm < M && gk < K) va = *(const short8*)(A + (size_t)gm * lda + gk);
            *(short8*)(&As[row][k0]) = va;
            short8 vb = {};
            const int gn = n0 + row;
            if (gn < N && gk < K) vb = *(const short8*)(B + (size_t)gn * ldb + gk);
            *(short8*)(&Bs[row][k0]) = vb;
        }
        __syncthreads();
#pragma unroll
        for (int kk = 0; kk < 2; ++kk) {
            short8 a0 = *(const short8*)(&As[wm * 32 +  0 + lr][kk * 32 + lg * 8]);
            short8 a1 = *(const short8*)(&As[wm * 32 + 16 + lr][kk * 32 + lg * 8]);
            short8 b0 = *(const short8*)(&Bs[wn * 32 +  0 + lr][kk * 32 + lg * 8]);
            short8 b1 = *(const short8*)(&Bs[wn * 32 + 16 + lr][kk * 32 + lg * 8]);
            mfma_bf16(acc[0][0], a0, b0);
            mfma_bf16(acc[0][1], a0, b1);
            mfma_bf16(acc[1][0], a1, b0);
            mfma_bf16(acc[1][1], a1, b1);
        }
        __syncthreads();
    }

#pragma unroll
    for (int mf = 0; mf < 2; ++mf)
#pragma unroll
        for (int nf = 0; nf < 2; ++nf) {
            const int gc = n0 + wn * 32 + nf * 16 + lr;
            if (gc >= N) continue;
#pragma unroll
            for (int r = 0; r < 4; ++r) {
                const int gm = m0 + wm * 32 + mf * 16 + lg * 4 + r;
                if (gm >= M) continue;
                float v = acc[mf][nf][r];
                const size_t oi = (size_t)gm * ldc + gc;
                if constexpr (EPI == 0) {
                    ((ushort_t*)C)[oi] = f2bf(v);
                } else {
                    v += bias[gc];
                    v = (v > 20.0f) ? v : log1pf(__expf(v));
                    ((ushort_t*)C)[oi] = f2bf(v);
                }
            }
        }
}

// ---------------- depthwise causal conv (DC=4) + SiLU, gathered from xz0 ----------------
__global__ void k_conv(const ushort_t* __restrict__ xz0, const float* __restrict__ cw,
                       const float* __restrict__ cb, ushort_t* __restrict__ xi) {
    const int idx = blockIdx.x * 256 + threadIdx.x;
    if (idx >= MTOK * DI) return;
    const int ch = idx & (DI - 1);
    const int l  = (idx >> 10) % Lq;
    const int s  = idx / (DI * Lq);
    const int p  = s / Bm, bi = s % Bm;
    const float4 wv = *(const float4*)(cw + ch * 4);
    float a = cb[ch];
    {   // tap d=0 (current)
        const int tok = path_tok(p, bi, l);
        a += bf2f(xz0[(size_t)tok * (2 * DI) + ch]) * wv.w;
    }
    if (l >= 1) { const int tok = path_tok(p, bi, l - 1); a += bf2f(xz0[(size_t)tok * (2 * DI) + ch]) * wv.z; }
    if (l >= 2) { const int tok = path_tok(p, bi, l - 2); a += bf2f(xz0[(size_t)tok * (2 * DI) + ch]) * wv.y; }
    if (l >= 3) { const int tok = path_tok(p, bi, l - 3); a += bf2f(xz0[(size_t)tok * (2 * DI) + ch]) * wv.x; }
    const float sv = a / (1.0f + __expf(-a));
    xi[(size_t)(s * Lq + l) * DI + ch] = f2bf(sv);
}

// ---------------- chunked selective scan ----------------
__global__ void k_scan1(const ushort_t* __restrict__ dt, const ushort_t* __restrict__ xz0,
                        const ushort_t* __restrict__ xdbl, const float* __restrict__ A_log,
                        const float* __restrict__ Dp, ushort_t* __restrict__ xiy,
                        ushort_t* __restrict__ corr, float* __restrict__ Pb,
                        float* __restrict__ Sb) {
    const int blk = blockIdx.x;                    // s*128 + j*16 + cg
    const int s  = blk >> 7;
    const int j  = (blk >> 4) & 7;
    const int ch = ((blk & 15) << 6) + threadIdx.x;
    const int p  = s / Bm, bi = s % Bm;
    const int gl0 = j * CHK;
    const float Av = -__expf(A_log[ch]);
    const float Dv = Dp[ch];
    const size_t tok0 = (size_t)s * Lq + (size_t)gl0;
    const ushort_t* pdt = dt  + tok0 * DI + ch;
    ushort_t*       pxi = xiy + tok0 * DI + ch;
    ushort_t*       pco = corr + tok0 * DI + ch;
    const ushort_t* pbc = xdbl + tok0 * XD_LD;

    float h = 0.0f, pp = 1.0f;
    float dtv = bf2f(pdt[0]);
    float xiv = bf2f(pxi[0]);
    float zv  = bf2f(xz0[(size_t)path_tok(p, bi, gl0) * (2 * DI) + DI + ch]);
    float bc  = bf2f(pbc[32]);
    float cc  = bf2f(pbc[33]);
    for (int l = 0; l < CHK; ++l) {
        float ndt = 0.f, nxi = 0.f, nz = 0.f, nbc = 0.f, ncc = 0.f;
        if (l + 1 < CHK) {
            const size_t o = (size_t)(l + 1);
            ndt = bf2f(pdt[o * DI]);
            nxi = bf2f(pxi[o * DI]);
            nz  = bf2f(xz0[(size_t)path_tok(p, bi, gl0 + l + 1) * (2 * DI) + DI + ch]);
            nbc = bf2f(pbc[o * XD_LD + 32]);
            ncc = bf2f(pbc[o * XD_LD + 33]);
        }
        const float dA = __expf(dtv * Av);
        h = dA * h + dtv * bc * xiv;
        pp *= dA;
        const float sz = zv / (1.0f + __expf(-zv));
        pxi[(size_t)l * DI] = f2bf((cc * h + Dv * xiv) * sz);
        pco[(size_t)l * DI] = f2bf(cc * pp * sz);
        dtv = ndt; xiv = nxi; zv = nz; bc = nbc; cc = ncc;
    }
    const size_t pi = (size_t)(s * NCHK + j) * DI + ch;
    Pb[pi] = pp;
    Sb[pi] = h;
}

__global__ void k_scan2(const float* __restrict__ Pb, const float* __restrict__ Sb,
                        float* __restrict__ cb) {
    const int s  = blockIdx.x >> 4;
    const int ch = ((blockIdx.x & 15) << 6) + threadIdx.x;
    float c = 0.0f;
#pragma unroll
    for (int j = 0; j < NCHK; ++j) {
        const size_t pi = (size_t)(s * NCHK + j) * DI + ch;
        cb[pi] = c;
        c = Pb[pi] * c + Sb[pi];
    }
}

__global__ void k_scan3(ushort_t* __restrict__ y, const ushort_t* __restrict__ corr,
                        const float* __restrict__ cb) {
    const int idx = blockIdx.x * 256 + threadIdx.x;   // MTOK*DI/8 total
    const int tok = idx >> 7;
    const int ch0 = (idx & 127) << 3;
    const int s   = tok / Lq;
    const int j   = (tok % Lq) / CHK;
    const size_t off = (size_t)tok * DI + ch0;
    union U { uint4 u; ushort_t h[8]; };
    U yv, cv, ov;
    yv.u = *(const uint4*)(y + off);
    cv.u = *(const uint4*)(corr + off);
    const float* cp = cb + (size_t)(s * NCHK + j) * DI + ch0;
    float4 c0 = *(const float4*)(cp);
    float4 c1 = *(const float4*)(cp + 4);
    ov.h[0] = f2bf(bf2f(yv.h[0]) + c0.x * bf2f(cv.h[0]));
    ov.h[1] = f2bf(bf2f(yv.h[1]) + c0.y * bf2f(cv.h[1]));
    ov.h[2] = f2bf(bf2f(yv.h[2]) + c0.z * bf2f(cv.h[2]));
    ov.h[3] = f2bf(bf2f(yv.h[3]) + c0.w * bf2f(cv.h[3]));
    ov.h[4] = f2bf(bf2f(yv.h[4]) + c1.x * bf2f(cv.h[4]));
    ov.h[5] = f2bf(bf2f(yv.h[5]) + c1.y * bf2f(cv.h[5]));
    ov.h[6] = f2bf(bf2f(yv.h[6]) + c1.z * bf2f(cv.h[6]));
    ov.h[7] = f2bf(bf2f(yv.h[7]) + c1.w * bf2f(cv.h[7]));
    *(uint4*)(y + off) = ov.u;
}

// ---------------- 4-path gather-sum (pre-out-proj) ----------------
__global__ void k_ysum(const ushort_t* __restrict__ y, ushort_t* __restrict__ ys) {
    const int tok = blockIdx.x;      // NTOK
    const int c0  = threadIdx.x * 8; // 128 threads * 8 = 1024 ch
    const int bi = tok / Lq;
    const int l1 = tok % Lq;
    const int t  = l1 / (Hh * Wd);
    const int hw = l1 % (Hh * Wd);
    const int hh = hw / Wd, ww = hw % Wd;
    const int l3 = (t * Wd + ww) * Hh + hh;
    union U { uint4 u; ushort_t h[8]; };
    U u0, u1, u2, u3, ov;
    u0.u = *(const uint4*)(y + ((size_t)(0 * Bm + bi) * Lq + l1           ) * DI + c0);
    u1.u = *(const uint4*)(y + ((size_t)(1 * Bm + bi) * Lq + (Lq - 1 - l1)) * DI + c0);
    u2.u = *(const uint4*)(y + ((size_t)(2 * Bm + bi) * Lq + l3           ) * DI + c0);
    u3.u = *(const uint4*)(y + ((size_t)(3 * Bm + bi) * Lq + (Lq - 1 - l3)) * DI + c0);
#pragma unroll
    for (int k = 0; k < 8; ++k)
        ov.h[k] = f2bf(bf2f(u0.h[k]) + bf2f(u1.h[k]) + bf2f(u2.h[k]) + bf2f(u3.h[k]));
    *(uint4*)(ys + (size_t)tok * DI + c0) = ov.u;
}

// ---------------- LN2 ----------------
__global__ void k_ln2(const float* __restrict__ xin, const float* __restrict__ g,
                      const float* __restrict__ b, ushort_t* __restrict__ out) {
    const int tok  = blockIdx.x;
    const int lane = threadIdx.x;
    const int c0   = lane * 8;
    const float* row = xin + (size_t)tok * Dm;
    float4 v0 = *(const float4*)(row + c0);
    float4 v1 = *(const float4*)(row + c0 + 4);
    float s  = v0.x + v0.y + v0.z + v0.w + v1.x + v1.y + v1.z + v1.w;
    float ss = v0.x*v0.x + v0.y*v0.y + v0.z*v0.z + v0.w*v0.w
             + v1.x*v1.x + v1.y*v1.y + v1.z*v1.z + v1.w*v1.w;
#pragma unroll
    for (int o = 32; o >= 1; o >>= 1) { s += __shfl_xor(s, o); ss += __shfl_xor(ss, o); }
    const float mean = s * (1.0f / Dm);
    const float rstd = rsqrtf(ss * (1.0f / Dm) - mean * mean + 1e-5f);
    float4 g0 = *(const float4*)(g + c0), g1 = *(const float4*)(g + c0 + 4);
    float4 b0 = *(const float4*)(b + c0), b1 = *(const float4*)(b + c0 + 4);
    union { uint4 u; ushort_t h[8]; } pk;
    pk.h[0] = f2bf((v0.x - mean) * rstd * g0.x + b0.x);
    pk.h[1] = f2bf((v0.y - mean) * rstd * g0.y + b0.y);
    pk.h[2] = f2bf((v0.z - mean) * rstd * g0.z + b0.z);
    pk.h[3] = f2bf((v0.w - mean) * rstd * g0.w + b0.w);
    pk.h[4] = f2bf((v1.x - mean) * rstd * g1.x + b1.x);
    pk.h[5] = f2bf((v1.y - mean) * rstd * g1.y + b1.y);
    pk.h[6] = f2bf((v1.z - mean) * rstd * g1.z + b1.z);
    pk.h[7] = f2bf((v1.w - mean) * rstd * g1.w + b1.w);
    *(uint4*)(out + (size_t)tok * Dm + c0) = pk.u;
}

// ---------------- workspace layout (no aliasing; ~222 MB) ----------------
constexpr size_t OFF_CAT = 0;                                 // ln1 out, MPAD x Dm bf16
constexpr size_t SZ_CAT  = (size_t)MPAD * Dm * 2;
constexpr size_t OFF_XZ0 = OFF_CAT + SZ_CAT;                  // in-proj out, MPAD x 2DI bf16
constexpr size_t SZ_XZ0  = (size_t)MPAD * 2 * DI * 2;
constexpr size_t OFF_XI  = OFF_XZ0 + SZ_XZ0;                  // conv out / y, MTOK x DI bf16
constexpr size_t SZ_XI   = (size_t)MTOK * DI * 2;
constexpr size_t OFF_XD  = OFF_XI + SZ_XI;                    // x_dbl, MTOK x 40 bf16
constexpr size_t SZ_XD   = (size_t)MTOK * XD_LD * 2;
constexpr size_t OFF_DT  = OFF_XD + SZ_XD;                    // dt, MTOK x DI bf16
constexpr size_t SZ_DT   = (size_t)MTOK * DI * 2;
constexpr size_t OFF_CO  = OFF_DT + SZ_DT;                    // corr, MTOK x DI bf16
constexpr size_t SZ_CO   = (size_t)MTOK * DI * 2;
constexpr size_t SZ_PSC  = (size_t)MBAT * NCHK * DI * 4;
constexpr size_t OFF_P   = OFF_CO + SZ_CO;
constexpr size_t OFF_S   = OFF_P + SZ_PSC;
constexpr size_t OFF_C   = OFF_S + SZ_PSC;
constexpr size_t OFF_YS  = OFF_C + SZ_PSC;                    // ysum, MPAD x DI bf16
constexpr size_t SZ_YS   = (size_t)MPAD * DI * 2;
constexpr size_t OFF_XR2 = OFF_YS + SZ_YS;                    // xr2, NTOK x Dm f32
constexpr size_t SZ_XR2  = (size_t)NTOK * Dm * 4;
constexpr size_t OFF_XL2 = OFF_XR2 + SZ_XR2;                  // ln2 out, MPAD x Dm bf16
constexpr size_t SZ_XL2  = (size_t)MPAD * Dm * 2;
constexpr size_t OFF_HM  = OFF_XL2 + SZ_XL2;                  // hmid, MPAD x 4Dm bf16
constexpr size_t SZ_HM   = (size_t)MPAD * 4 * Dm * 2;
constexpr size_t OFF_WIN = OFF_HM + SZ_HM;
constexpr size_t OFF_WOUT= OFF_WIN  + (size_t)2 * DI * Dm * 2;
constexpr size_t OFF_W1  = OFF_WOUT + (size_t)Dm * DI * 2;
constexpr size_t OFF_W2  = OFF_W1   + (size_t)4 * Dm * Dm * 2;
constexpr size_t OFF_WXP = OFF_W2   + (size_t)Dm * 4 * Dm * 2;
constexpr size_t OFF_WDT = OFF_WXP  + (size_t)(DR + 2) * DI * 2;
constexpr size_t WS_NEED = OFF_WDT  + (size_t)DI * DR * 2;

extern "C" void kernel_launch(void* const* d_in, const int* in_sizes, int n_in,
                              void* d_out, int out_size, void* d_ws, size_t ws_size,
                              hipStream_t stream) {
    const float* x        = (const float*)d_in[0];
    const float* ln1_g    = (const float*)d_in[1];
    const float* ln1_b    = (const float*)d_in[2];
    const float* ln2_g    = (const float*)d_in[3];
    const float* ln2_b    = (const float*)d_in[4];
    const float* mlp_w1   = (const float*)d_in[5];
    const float* mlp_b1   = (const float*)d_in[6];
    const float* mlp_w2   = (const float*)d_in[7];
    const float* mlp_b2   = (const float*)d_in[8];
    const float* in_w     = (const float*)d_in[9];
    const float* conv_w   = (const float*)d_in[10];
    const float* conv_b   = (const float*)d_in[11];
    const float* xproj_w  = (const float*)d_in[12];
    const float* dtproj_w = (const float*)d_in[13];
    const float* dtproj_b = (const float*)d_in[14];
    const float* A_log    = (const float*)d_in[15];
    const float* D_param  = (const float*)d_in[16];
    const float* out_w    = (const float*)d_in[17];

    if (ws_size < WS_NEED) return;  // loud failure (d_out stays zero)

    char* ws = (char*)d_ws;
    ushort_t* cat   = (ushort_t*)(ws + OFF_CAT);
    ushort_t* xz0   = (ushort_t*)(ws + OFF_XZ0);
    ushort_t* xi    = (ushort_t*)(ws + OFF_XI);
    ushort_t* xdbl  = (ushort_t*)(ws + OFF_XD);
    ushort_t* dtb   = (ushort_t*)(ws + OFF_DT);
    ushort_t* corr  = (ushort_t*)(ws + OFF_CO);
    float*    Pb    = (float*)   (ws + OFF_P);
    float*    Sb    = (float*)   (ws + OFF_S);
    float*    cb    = (float*)   (ws + OFF_C);
    ushort_t* ysum  = (ushort_t*)(ws + OFF_YS);
    float*    xr2   = (float*)   (ws + OFF_XR2);
    ushort_t* xln2  = (ushort_t*)(ws + OFF_XL2);
    ushort_t* hmid  = (ushort_t*)(ws + OFF_HM);
    ushort_t* w_in  = (ushort_t*)(ws + OFF_WIN);
    ushort_t* w_out = (ushort_t*)(ws + OFF_WOUT);
    ushort_t* w_1   = (ushort_t*)(ws + OFF_W1);
    ushort_t* w_2   = (ushort_t*)(ws + OFF_W2);
    ushort_t* w_xp  = (ushort_t*)(ws + OFF_WXP);
    ushort_t* w_dt  = (ushort_t*)(ws + OFF_WDT);

    auto cvt = [&](const float* s, ushort_t* d, int n) {
        k_f2bf<<<(n + 255) / 256, 256, 0, stream>>>(s, d, n);
    };
    cvt(in_w,     w_in,  2 * DI * Dm);
    cvt(out_w,    w_out, Dm * DI);
    cvt(mlp_w1,   w_1,   4 * Dm * Dm);
    cvt(mlp_w2,   w_2,   Dm * 4 * Dm);
    cvt(xproj_w,  w_xp,  (DR + 2) * DI);
    cvt(dtproj_w, w_dt,  DI * DR);

    // LN1 (per-token, single copy)
    k_ln1<<<NTOK, 64, 0, stream>>>(x, ln1_g, ln1_b, cat);

    // xz0 = ln1(x) @ in_w^T   (5280 x 2048, K=512) — 4x dedup
    k_gemm128<128, 128, 0><<<dim3(MPAD / 128, (2 * DI) / 128), 256, 0, stream>>>(
        cat, w_in, xz0, NTOK, 2 * DI, Dm, Dm, Dm, 2 * DI, nullptr, nullptr);

    // depthwise causal conv + SiLU -> xi (path-ordered, gathered from xz0)
    k_conv<<<(MTOK * DI + 255) / 256, 256, 0, stream>>>(xz0, conv_w, conv_b, xi);

    // x_dbl = xi @ xproj^T  (N=34, padded ld 40)
    k_gemm_bt<0><<<dim3(MTOK / 64, 1), 256, 0, stream>>>(
        xi, w_xp, xdbl, MTOK, DR + 2, DI, DI, DI, XD_LD, nullptr);

    // dt = softplus(x_dbl[:, :32] @ dtproj^T + b)  (bf16, K=32)
    k_gemm_bt<1><<<dim3(MTOK / 64, DI / 64), 256, 0, stream>>>(
        xdbl, w_dt, dtb, MTOK, DI, DR, XD_LD, DR, DI, dtproj_b);

    // chunked selective scan (z gathered from xz0)
    k_scan1<<<MBAT * NCHK * 16, 64, 0, stream>>>(dtb, xz0, xdbl, A_log, D_param,
                                                 xi, corr, Pb, Sb);
    k_scan2<<<MBAT * 16, 64, 0, stream>>>(Pb, Sb, cb);
    k_scan3<<<(MTOK * DI / 8) / 256, 256, 0, stream>>>(xi, corr, cb);

    // ysum = sum of 4 path-gathered y's  (5280 x 1024)
    k_ysum<<<NTOK, 128, 0, stream>>>(xi, ysum);

    // xr2 = x + ysum @ out_w^T   (M=5280, 4x dedup + fused residual)
    k_gemm128<128, 128, 4><<<dim3(MPAD / 128, Dm / 128), 256, 0, stream>>>(
        ysum, w_out, xr2, NTOK, Dm, DI, DI, DI, Dm, nullptr, x);

    // LN2
    k_ln2<<<NTOK, 64, 0, stream>>>(xr2, ln2_g, ln2_b, xln2);

    // hmid = gelu(xln2 @ w1^T + b1)
    k_gemm128<128, 128, 2><<<dim3(MPAD / 128, (4 * Dm) / 128), 256, 0, stream>>>(
        xln2, w_1, hmid, NTOK, 4 * Dm, Dm, Dm, Dm, 4 * Dm, mlp_b1, nullptr);

    // out = xr2 + hmid @ w2^T + b2  -> f32 d_out
    k_gemm128<128, 128, 3><<<dim3(MPAD / 128, Dm / 128), 256, 0, stream>>>(
        hmid, w_2, (float*)d_out, NTOK, Dm, 4 * Dm, 4 * Dm, 4 * Dm, Dm, mlp_b2, xr2);
}